// Round 1
// baseline (17242.053 us; speedup 1.0000x reference)
//
#include <hip/hip_runtime.h>
#include <hip/hip_bf16.h>
#include <cstdint>
#include <cstddef>

#define B_    32
#define S_    512
#define IN_   256
#define HID_  512
#define KTOT  768        // IN_ + HID_
#define NGATE 1024
#define OUT_  256
#define NWG   16         // workgroups per direction
#define GCOLS 64         // gate cols per WG
#define CCOLS 32         // candidate cols per WG
#define KK    24         // k-iters of 32 over KTOT
#define KKX   8          // k-iters covering the x region (256/32)

typedef float f32x4 __attribute__((ext_vector_type(4)));
typedef short bf16x8 __attribute__((ext_vector_type(8)));

__device__ inline unsigned short f2bf(float f) {
  return __builtin_bit_cast(unsigned short, __float2bfloat16(f));
}

// ---------------------------------------------------------------- prep ----
// Fills FW/BW x-regions (bf16), zeros h seeds / hfp / pool / barrier
// counters, and swizzles fc_w into MFMA B-fragment order (bf16).
__global__ void prep_kernel(const float* __restrict__ x,
                            const float* __restrict__ fcw,
                            unsigned short* __restrict__ FW,
                            unsigned short* __restrict__ BW,
                            float* __restrict__ hfp,
                            float* __restrict__ pool,
                            unsigned* __restrict__ bars,
                            unsigned short* __restrict__ fcwf)
{
  const int nthreads = gridDim.x * blockDim.x;
  const int gtid = blockIdx.x * blockDim.x + threadIdx.x;

  // x -> FW/BW x-part.  x is [B,S,IN]; slots are [S][B][KTOT].
  for (int i = gtid; i < S_*B_*IN_; i += nthreads) {
    int c = i & (IN_-1);
    int rem = i >> 8;            // / IN_
    int b = rem & (B_-1);
    int s = rem >> 5;            // / B_
    unsigned short v = f2bf(x[((size_t)b*S_ + s)*IN_ + c]);
    size_t o = ((size_t)s*B_ + b)*KTOT + c;
    FW[o] = v; BW[o] = v;
  }
  // zero FW[0].h (h_{-1}=0) and BW[S-1].h (hb_S=0)
  for (int i = gtid; i < B_*HID_; i += nthreads) {
    int b = i >> 9, j = i & (HID_-1);
    FW[(size_t)b*KTOT + IN_ + j] = 0;
    BW[((size_t)(S_-1)*B_ + b)*KTOT + IN_ + j] = 0;
  }
  for (int i = gtid; i < 2*B_*HID_; i += nthreads) hfp[i] = 0.f;
  for (int i = gtid; i < B_*HID_;   i += nthreads) pool[i] = 0.f;
  for (int i = gtid; i < 64;        i += nthreads) bars[i] = 0u;
  // fc_w [1280][512] -> fragment order [kc=40][nt=32][lane=64][8]
  for (int i = gtid; i < 40*32*64*8; i += nthreads) {
    int j     = i & 7;
    int lane_ = (i >> 3) & 63;
    int nt    = (i >> 9) & 31;
    int kc    = i >> 14;
    int k = kc*32 + (lane_ >> 4)*8 + j;
    int n = nt*16 + (lane_ & 15);
    fcwf[i] = f2bf(fcw[(size_t)k*HID_ + n]);
  }
}

// ----------------------------------------------------------- barrier ----
__device__ inline void gbar(unsigned* bar, unsigned target) {
  __threadfence();
  __syncthreads();
  if (threadIdx.x == 0) {
    __hip_atomic_fetch_add(bar, 1u, __ATOMIC_ACQ_REL, __HIP_MEMORY_SCOPE_AGENT);
    unsigned v;
    do {
      v = __hip_atomic_load(bar, __ATOMIC_RELAXED, __HIP_MEMORY_SCOPE_AGENT);
      if (v < target) __builtin_amdgcn_s_sleep(1);
    } while (v < target);
  }
  __syncthreads();
  __threadfence();
}

// --------------------------------------------------------------- gru ----
// 32 blocks: blockIdx>>4 = direction, &15 = column-slice id.  Weight
// slices live in LDS (MFMA B-frag layout) for all 512 steps.
__global__ __launch_bounds__(512, 1)
void gru_kernel(const float* __restrict__ Wg_fw, const float* __restrict__ bg_fw,
                const float* __restrict__ Wc_fw, const float* __restrict__ bc_fw,
                const float* __restrict__ Wg_bw, const float* __restrict__ bg_bw,
                const float* __restrict__ Wc_bw, const float* __restrict__ bc_bw,
                unsigned short* __restrict__ FW, unsigned short* __restrict__ BW,
                float* __restrict__ hfp, unsigned short* __restrict__ rhbuf,
                float* __restrict__ ubuf, unsigned* __restrict__ bars)
{
  __shared__ unsigned short lds[73728];   // 96KB Wg-frags + 48KB Wc-frags
  const int dir = blockIdx.x >> 4;
  const int g   = blockIdx.x & 15;
  const int tid = threadIdx.x;
  const int wave = tid >> 6, lane = tid & 63;
  const int quad = lane >> 4, l16 = lane & 15;

  const float* Wg = dir ? Wg_bw : Wg_fw;
  const float* Wc = dir ? Wc_bw : Wc_fw;
  const float* bg = dir ? bg_bw : bg_fw;
  const float* bc = dir ? bc_bw : bc_fw;
  unsigned short* SLOT = dir ? BW : FW;          // [S][B][KTOT]
  float*          h    = hfp   + dir*(B_*HID_);  // fp32 master state
  unsigned short* rh   = rhbuf + dir*(B_*HID_);  // bf16 r*h
  float*          ub   = ubuf  + dir*(B_*HID_);  // fp32 u gate
  unsigned*       bar  = bars  + dir*32;

  // ---- stage weight slices into LDS as B-fragments (one time) ----
  for (int idx = tid; idx < KK*4*64; idx += 512) {
    int lane_ = idx & 63, nt = (idx >> 6) & 3, kk = idx >> 8;
    int n  = g*GCOLS + nt*16 + (lane_ & 15);
    int kb = kk*32 + (lane_ >> 4)*8;
    #pragma unroll
    for (int j = 0; j < 8; ++j)
      lds[idx*8 + j] = f2bf(Wg[(size_t)(kb + j)*NGATE + n]);
  }
  for (int idx = tid; idx < KK*2*64; idx += 512) {
    int lane_ = idx & 63, nt = (idx >> 6) & 1, kk = idx >> 7;
    int n  = g*CCOLS + nt*16 + (lane_ & 15);
    int kb = kk*32 + (lane_ >> 4)*8;
    #pragma unroll
    for (int j = 0; j < 8; ++j)
      lds[49152 + idx*8 + j] = f2bf(Wc[(size_t)(kb + j)*HID_ + n]);
  }
  __syncthreads();

  for (int si = 0; si < S_; ++si) {
    const int t  = dir ? (S_-1-si) : si;
    const int to = dir ? (t-1)     : (t+1);   // output slot
    const unsigned short* in = SLOT + (size_t)t*B_*KTOT;  // [x_t | h_prev]

    { // ---- phase A: gates = sigmoid([x,h]@Wg + bg) ----
      const int nt = wave & 3, mt = wave >> 2;  // 8 waves cover 4nt x 2mt
      f32x4 acc = {0.f,0.f,0.f,0.f};
      const unsigned short* arow = in + (mt*16 + l16)*KTOT + quad*8;
      #pragma unroll
      for (int kk = 0; kk < KK; ++kk) {
        bf16x8 af  = *(const bf16x8*)(arow + kk*32);
        bf16x8 bfv = *(const bf16x8*)(&lds[((kk*4 + nt)*64 + lane)*8]);
        acc = __builtin_amdgcn_mfma_f32_16x16x32_bf16(af, bfv, acc, 0, 0, 0);
      }
      const int col = g*GCOLS + nt*16 + l16;    // 0..1023
      const float bgv = bg[col];
      #pragma unroll
      for (int r = 0; r < 4; ++r) {
        const int b = mt*16 + quad*4 + r;       // C/D: row = quad*4+reg
        float v = 1.f / (1.f + __expf(-(acc[r] + bgv)));
        if (col < HID_) rh[b*HID_ + col] = f2bf(v * h[b*HID_ + col]);
        else            ub[b*HID_ + col - HID_] = v;
      }
    }
    gbar(bar, (unsigned)(NWG*(2*si + 1)));

    if (wave < 4) { // ---- phase B: c = tanh([x, r*h]@Wc + bc); h update ----
      const int nt = wave & 1, mt = wave >> 1;  // 4 waves cover 2nt x 2mt
      f32x4 acc = {0.f,0.f,0.f,0.f};
      const unsigned short* axrow = in + (mt*16 + l16)*KTOT + quad*8;
      const unsigned short* ahrow = rh + (mt*16 + l16)*HID_ + quad*8;
      #pragma unroll
      for (int kk = 0; kk < KK; ++kk) {
        bf16x8 af = (kk < KKX) ? *(const bf16x8*)(axrow + kk*32)
                               : *(const bf16x8*)(ahrow + (kk - KKX)*32);
        bf16x8 bfv = *(const bf16x8*)(&lds[49152 + ((kk*2 + nt)*64 + lane)*8]);
        acc = __builtin_amdgcn_mfma_f32_16x16x32_bf16(af, bfv, acc, 0, 0, 0);
      }
      const int col = g*CCOLS + nt*16 + l16;    // 0..511
      const float bcv = bc[col];
      #pragma unroll
      for (int r = 0; r < 4; ++r) {
        const int b = mt*16 + quad*4 + r;
        const float c = tanhf(acc[r] + bcv);
        const float u = ub[b*HID_ + col];
        const float hn = u * h[b*HID_ + col] + (1.f - u)*c;
        h[b*HID_ + col] = hn;
        if (to >= 0 && to < S_)
          SLOT[(size_t)to*B_*KTOT + b*KTOT + IN_ + col] = f2bf(hn);
      }
    }
    gbar(bar, (unsigned)(NWG*(2*si + 2)));
  }
}

// ---------------------------------------------------------------- fc ----
// last[b][t] = [FW[t].h | FW[t].x | BW[t].h]; pool = max_t relu(last@fcw+fcb)
__global__ __launch_bounds__(512, 1)
void fc_kernel(const unsigned short* __restrict__ FW, const unsigned short* __restrict__ BW,
               const unsigned short* __restrict__ fcwf, const float* __restrict__ fcb,
               float* __restrict__ pool)
{
  __shared__ unsigned short bsm[32*512];   // 32KB weight chunk (frag order)
  __shared__ float red[8*512];             // 16KB cross-wave max reduce
  const int wg = blockIdx.x;               // 128 WGs: b = wg/4, t-quarter = wg%4
  const int b  = wg >> 2;
  const int tid = threadIdx.x, wave = tid >> 6, lane = tid & 63;
  const int quad = lane >> 4, l16 = lane & 15;
  const int t = (wg & 3)*128 + wave*16 + l16;  // A-operand row = t

  f32x4 acc[32];
  #pragma unroll
  for (int nt = 0; nt < 32; ++nt) acc[nt] = (f32x4){0.f,0.f,0.f,0.f};

  for (int kc = 0; kc < 40; ++kc) {
    __syncthreads();
    const uint4* src = (const uint4*)(fcwf + (size_t)kc*32*512);
    uint4* dst = (uint4*)bsm;
    #pragma unroll
    for (int r = 0; r < 4; ++r) dst[tid + r*512] = src[tid + r*512];
    __syncthreads();

    const unsigned short* ap;
    if (kc < 16)      ap = FW + ((size_t)t*B_ + b)*KTOT + IN_ + kc*32 + quad*8;       // c_left
    else if (kc < 24) ap = FW + ((size_t)t*B_ + b)*KTOT + (kc - 16)*32 + quad*8;      // x
    else              ap = BW + ((size_t)t*B_ + b)*KTOT + IN_ + (kc - 24)*32 + quad*8;// c_right
    const bf16x8 af = *(const bf16x8*)ap;
    #pragma unroll
    for (int nt = 0; nt < 32; ++nt) {
      bf16x8 bfv = *(const bf16x8*)(&bsm[(nt*64 + lane)*8]);
      acc[nt] = __builtin_amdgcn_mfma_f32_16x16x32_bf16(af, bfv, acc[nt], 0, 0, 0);
    }
  }
  // max over this wave's 16 t-rows, per column
  #pragma unroll
  for (int nt = 0; nt < 32; ++nt) {
    float m = fmaxf(fmaxf(acc[nt][0], acc[nt][1]), fmaxf(acc[nt][2], acc[nt][3]));
    m = fmaxf(m, __shfl_xor(m, 16, 64));
    m = fmaxf(m, __shfl_xor(m, 32, 64));
    if (quad == 0) red[wave*512 + nt*16 + l16] = m;
  }
  __syncthreads();
  {
    float m = red[tid];
    #pragma unroll
    for (int w = 1; w < 8; ++w) m = fmaxf(m, red[w*512 + tid]);
    m = fmaxf(m + fcb[tid], 0.f);   // bias then relu (pool init 0 keeps relu floor)
    atomicMax((int*)&pool[(size_t)b*HID_ + tid], __float_as_int(m));
  }
}

// --------------------------------------------------------------- mlp ----
__global__ void mlp_kernel(const float* __restrict__ pool, const float* __restrict__ w,
                           const float* __restrict__ bias, float* __restrict__ out)
{
  __shared__ float p[HID_];
  const int b = blockIdx.x, tid = threadIdx.x;  // 256 threads
  p[tid]       = pool[(size_t)b*HID_ + tid];
  p[tid + 256] = pool[(size_t)b*HID_ + 256 + tid];
  __syncthreads();
  float acc = bias[tid];
  for (int k = 0; k < HID_; ++k) acc += p[k] * w[(size_t)k*OUT_ + tid];
  out[(size_t)b*OUT_ + tid] = acc;
}

// ------------------------------------------------------------ launch ----
extern "C" void kernel_launch(void* const* d_in, const int* in_sizes, int n_in,
                              void* d_out, int out_size, void* d_ws, size_t ws_size,
                              hipStream_t stream)
{
  const float* x    = (const float*)d_in[0];
  const float* fwWg = (const float*)d_in[1];
  const float* fwbg = (const float*)d_in[2];
  const float* fwWc = (const float*)d_in[3];
  const float* fwbc = (const float*)d_in[4];
  const float* bwWg = (const float*)d_in[5];
  const float* bwbg = (const float*)d_in[6];
  const float* bwWc = (const float*)d_in[7];
  const float* bwbc = (const float*)d_in[8];
  const float* fcw  = (const float*)d_in[9];
  const float* fcb  = (const float*)d_in[10];
  const float* mlpw = (const float*)d_in[11];
  const float* mlpb = (const float*)d_in[12];
  float* out = (float*)d_out;

  char* p = (char*)d_ws;
  auto take = [&](size_t bytes) { char* r = p; p += (bytes + 255) & ~size_t(255); return r; };
  unsigned short* FW   = (unsigned short*)take((size_t)S_*B_*KTOT*2);   // 25.2MB
  unsigned short* BW   = (unsigned short*)take((size_t)S_*B_*KTOT*2);   // 25.2MB
  float*          hfp  = (float*)take((size_t)2*B_*HID_*4);
  unsigned short* rh   = (unsigned short*)take((size_t)2*B_*HID_*2);
  float*          ub   = (float*)take((size_t)2*B_*HID_*4);
  unsigned short* fcwf = (unsigned short*)take((size_t)40*32*64*8*2);   // 1.25MB
  float*          pool = (float*)take((size_t)B_*HID_*4);
  unsigned*       bars = (unsigned*)take(256);

  prep_kernel<<<2048, 256, 0, stream>>>(x, fcw, FW, BW, hfp, pool, bars, fcwf);
  gru_kernel<<<32, 512, 0, stream>>>(fwWg, fwbg, fwWc, fwbc,
                                     bwWg, bwbg, bwWc, bwbc,
                                     FW, BW, hfp, rh, ub, bars);
  fc_kernel<<<128, 512, 0, stream>>>(FW, BW, fcwf, fcb, pool);
  mlp_kernel<<<32, 256, 0, stream>>>(pool, mlpw, mlpb, out);
}

// Round 2
// 7298.271 us; speedup vs baseline: 2.3625x; 2.3625x over previous
//
#include <hip/hip_runtime.h>
#include <hip/hip_bf16.h>
#include <cstdint>
#include <cstddef>

#define B_    32
#define S_    512
#define IN_   256
#define HID_  512
#define KTOT  768        // IN_ + HID_
#define NGATE 1024
#define OUT_  256
#define NWG   16         // workgroups per direction
#define KK    24         // k-iters of 32 over KTOT
#define KKX   8          // k-iters covering the x region (256/32)

typedef float f32x4 __attribute__((ext_vector_type(4)));
typedef short bf16x8 __attribute__((ext_vector_type(8)));

__device__ inline unsigned short f2bf(float f) {
  return __builtin_bit_cast(unsigned short, __float2bfloat16(f));
}
__device__ inline float bf2f(unsigned short u) {
  union { float f; unsigned int i; } v; v.i = ((unsigned int)u) << 16; return v.f;
}

// write-through 2B store: bypasses L1/L2 dirty state, lands at coherent point.
__device__ inline void store_short_wt(unsigned short* p, unsigned short val) {
  unsigned int v = val;
  asm volatile("global_store_short %0, %1, off sc0 sc1" :: "v"(p), "v"(v) : "memory");
}

// ---------------------------------------------------------------- prep ----
__global__ void prep_kernel(const float* __restrict__ x,
                            const float* __restrict__ fcw,
                            unsigned short* __restrict__ FW,
                            unsigned short* __restrict__ BW,
                            float* __restrict__ pool,
                            unsigned* __restrict__ bars,
                            unsigned short* __restrict__ fcwf)
{
  const int nthreads = gridDim.x * blockDim.x;
  const int gtid = blockIdx.x * blockDim.x + threadIdx.x;

  // x -> FW/BW x-part.  x is [B,S,IN]; slots are [S][B][KTOT].
  for (int i = gtid; i < S_*B_*IN_; i += nthreads) {
    int c = i & (IN_-1);
    int rem = i >> 8;            // / IN_
    int b = rem & (B_-1);
    int s = rem >> 5;            // / B_
    unsigned short v = f2bf(x[((size_t)b*S_ + s)*IN_ + c]);
    size_t o = ((size_t)s*B_ + b)*KTOT + c;
    FW[o] = v; BW[o] = v;
  }
  // zero FW[0].h (h_{-1}=0) and BW[S-1].h (hb_S=0)
  for (int i = gtid; i < B_*HID_; i += nthreads) {
    int b = i >> 9, j = i & (HID_-1);
    FW[(size_t)b*KTOT + IN_ + j] = 0;
    BW[((size_t)(S_-1)*B_ + b)*KTOT + IN_ + j] = 0;
  }
  for (int i = gtid; i < B_*HID_; i += nthreads) pool[i] = 0.f;
  for (int i = gtid; i < 64;      i += nthreads) bars[i] = 0u;
  // fc_w [1280][512] -> fragment order [kc=40][nt=32][lane=64][8]
  for (int i = gtid; i < 40*32*64*8; i += nthreads) {
    int j     = i & 7;
    int lane_ = (i >> 3) & 63;
    int nt    = (i >> 9) & 31;
    int kc    = i >> 14;
    int k = kc*32 + (lane_ >> 4)*8 + j;
    int n = nt*16 + (lane_ & 15);
    fcwf[i] = f2bf(fcw[(size_t)k*HID_ + n]);
  }
}

// ----------------------------------------------------------- barrier ----
// Preconditions: all cross-WG data was stored write-through (sc0 sc1).
// __syncthreads() drains vmcnt -> stores are at the coherent point.
// Relaxed add + relaxed spin; single acquire fence (buffer_inv) makes
// remote write-through data visible to subsequent PLAIN loads.
__device__ inline void gbar(unsigned* bar, unsigned target) {
  __syncthreads();
  if (threadIdx.x == 0) {
    __hip_atomic_fetch_add(bar, 1u, __ATOMIC_RELAXED, __HIP_MEMORY_SCOPE_AGENT);
    unsigned v;
    do {
      v = __hip_atomic_load(bar, __ATOMIC_RELAXED, __HIP_MEMORY_SCOPE_AGENT);
      if (v < target) __builtin_amdgcn_s_sleep(1);
    } while (v < target);
    __builtin_amdgcn_fence(__ATOMIC_ACQUIRE, "agent");   // buffer_inv (no wbl2)
  }
  __syncthreads();
}

// --------------------------------------------------------------- gru ----
// 32 blocks: blockIdx>>4 = direction, &15 = column-slice id g.
// WG g owns gate cols {g*32..g*32+31 (r)} U {512+g*32.. (u)} and cand cols
// g*32..g*32+31, so the u gate never leaves the workgroup (LDS).
__global__ __launch_bounds__(512, 1)
void gru_kernel(const float* __restrict__ Wg_fw, const float* __restrict__ bg_fw,
                const float* __restrict__ Wc_fw, const float* __restrict__ bc_fw,
                const float* __restrict__ Wg_bw, const float* __restrict__ bg_bw,
                const float* __restrict__ Wc_bw, const float* __restrict__ bc_bw,
                unsigned short* __restrict__ FW, unsigned short* __restrict__ BW,
                unsigned short* __restrict__ rhbuf, unsigned* __restrict__ bars)
{
  __shared__ unsigned short lds[73728];   // 96KB Wg-frags + 48KB Wc-frags
  __shared__ float u_lds[B_*32];          // 4KB: u gate, WG-local
  const int dir = blockIdx.x >> 4;
  const int g   = blockIdx.x & 15;
  const int tid = threadIdx.x;
  const int wave = tid >> 6, lane = tid & 63;
  const int quad = lane >> 4, l16 = lane & 15;

  const float* Wg = dir ? Wg_bw : Wg_fw;
  const float* Wc = dir ? Wc_bw : Wc_fw;
  const float* bg = dir ? bg_bw : bg_fw;
  const float* bc = dir ? bc_bw : bc_fw;
  unsigned short* SLOT = dir ? BW : FW;          // [S][B][KTOT]
  unsigned short* rh   = rhbuf + dir*(B_*HID_);  // bf16 r*h (cross-WG, sc1)
  unsigned*       bar  = bars  + dir*32;

  // ---- stage weight slices into LDS as B-fragments (one time) ----
  // Wg: nt<2 -> r cols g*32+nt*16+l16 ; nt>=2 -> u cols 512+g*32+(nt-2)*16+l16
  for (int idx = tid; idx < KK*4*64; idx += 512) {
    int lane_ = idx & 63, nt = (idx >> 6) & 3, kk = idx >> 8;
    int l16_ = lane_ & 15;
    int n = (nt < 2) ? (g*32 + nt*16 + l16_) : (512 + g*32 + (nt-2)*16 + l16_);
    int kb = kk*32 + (lane_ >> 4)*8;
    #pragma unroll
    for (int j = 0; j < 8; ++j)
      lds[idx*8 + j] = f2bf(Wg[(size_t)(kb + j)*NGATE + n]);
  }
  for (int idx = tid; idx < KK*2*64; idx += 512) {
    int lane_ = idx & 63, nt = (idx >> 6) & 1, kk = idx >> 7;
    int n  = g*32 + nt*16 + (lane_ & 15);
    int kb = kk*32 + (lane_ >> 4)*8;
    #pragma unroll
    for (int j = 0; j < 8; ++j)
      lds[49152 + idx*8 + j] = f2bf(Wc[(size_t)(kb + j)*HID_ + n]);
  }
  __syncthreads();

  for (int si = 0; si < S_; ++si) {
    const int t  = dir ? (S_-1-si) : si;
    const int to = dir ? (t-1)     : (t+1);   // output slot
    const unsigned short* in = SLOT + (size_t)t*B_*KTOT;  // [x_t | h_prev]

    { // ---- phase A: gates = sigmoid([x,h]@Wg + bg) ----
      const int nt = wave & 3, mt = wave >> 2;  // 8 waves: 4nt x 2mt
      f32x4 acc = {0.f,0.f,0.f,0.f};
      const unsigned short* arow = in + (mt*16 + l16)*KTOT + quad*8;
      #pragma unroll
      for (int kk = 0; kk < KK; ++kk) {
        bf16x8 af  = *(const bf16x8*)(arow + kk*32);
        bf16x8 bfv = *(const bf16x8*)(&lds[((kk*4 + nt)*64 + lane)*8]);
        acc = __builtin_amdgcn_mfma_f32_16x16x32_bf16(af, bfv, acc, 0, 0, 0);
      }
      if (nt < 2) {                       // r gate -> rh (cross-WG)
        const int col = g*32 + nt*16 + l16;      // in [0,512)
        const float bgv = bg[col];
        #pragma unroll
        for (int r = 0; r < 4; ++r) {
          const int b = mt*16 + quad*4 + r;      // C/D: row = quad*4+reg
          float rv = 1.f / (1.f + __expf(-(acc[r] + bgv)));
          float hp = bf2f(in[b*KTOT + IN_ + col]);
          store_short_wt(&rh[b*HID_ + col], f2bf(rv * hp));
        }
      } else {                            // u gate -> LDS (WG-local)
        const int cl  = (nt - 2)*16 + l16;       // local col in [0,32)
        const float bgv = bg[512 + g*32 + cl];
        #pragma unroll
        for (int r = 0; r < 4; ++r) {
          const int b = mt*16 + quad*4 + r;
          u_lds[b*32 + cl] = 1.f / (1.f + __expf(-(acc[r] + bgv)));
        }
      }
    }
    gbar(bar, (unsigned)(NWG*(2*si + 1)));

    if (wave < 4) { // ---- phase B: c = tanh([x, r*h]@Wc + bc); h update ----
      const int nt = wave & 1, mt = wave >> 1;  // 4 waves: 2nt x 2mt
      f32x4 acc = {0.f,0.f,0.f,0.f};
      const unsigned short* axrow = in + (mt*16 + l16)*KTOT + quad*8;
      const unsigned short* ahrow = rh + (mt*16 + l16)*HID_ + quad*8;
      #pragma unroll
      for (int kk = 0; kk < KK; ++kk) {
        bf16x8 af = (kk < KKX) ? *(const bf16x8*)(axrow + kk*32)
                               : *(const bf16x8*)(ahrow + (kk - KKX)*32);
        bf16x8 bfv = *(const bf16x8*)(&lds[49152 + ((kk*2 + nt)*64 + lane)*8]);
        acc = __builtin_amdgcn_mfma_f32_16x16x32_bf16(af, bfv, acc, 0, 0, 0);
      }
      const int cl  = nt*16 + l16;              // local col in [0,32)
      const int col = g*32 + cl;                // in [0,512)
      const float bcv = bc[col];
      #pragma unroll
      for (int r = 0; r < 4; ++r) {
        const int b = mt*16 + quad*4 + r;
        const float c = tanhf(acc[r] + bcv);
        const float u = u_lds[b*32 + cl];
        const float hp = bf2f(in[b*KTOT + IN_ + col]);
        const float hn = u * hp + (1.f - u)*c;
        if (to >= 0 && to < S_)
          store_short_wt(&SLOT[(size_t)to*B_*KTOT + b*KTOT + IN_ + col], f2bf(hn));
      }
    }
    gbar(bar, (unsigned)(NWG*(2*si + 2)));
  }
}

// ---------------------------------------------------------------- fc ----
// last[b][t] = [FW[t].h | FW[t].x | BW[t].h]; pool = max_t relu(last@fcw+fcb)
__global__ __launch_bounds__(512, 1)
void fc_kernel(const unsigned short* __restrict__ FW, const unsigned short* __restrict__ BW,
               const unsigned short* __restrict__ fcwf, const float* __restrict__ fcb,
               float* __restrict__ pool)
{
  __shared__ unsigned short bsm[32*512];   // 32KB weight chunk (frag order)
  __shared__ float red[8*512];             // 16KB cross-wave max reduce
  const int wg = blockIdx.x;               // 128 WGs: b = wg/4, t-quarter = wg%4
  const int b  = wg >> 2;
  const int tid = threadIdx.x, wave = tid >> 6, lane = tid & 63;
  const int quad = lane >> 4, l16 = lane & 15;
  const int t = (wg & 3)*128 + wave*16 + l16;  // A-operand row = t

  f32x4 acc[32];
  #pragma unroll
  for (int nt = 0; nt < 32; ++nt) acc[nt] = (f32x4){0.f,0.f,0.f,0.f};

  for (int kc = 0; kc < 40; ++kc) {
    __syncthreads();
    const uint4* src = (const uint4*)(fcwf + (size_t)kc*32*512);
    uint4* dst = (uint4*)bsm;
    #pragma unroll
    for (int r = 0; r < 4; ++r) dst[tid + r*512] = src[tid + r*512];
    __syncthreads();

    const unsigned short* ap;
    if (kc < 16)      ap = FW + ((size_t)t*B_ + b)*KTOT + IN_ + kc*32 + quad*8;       // c_left
    else if (kc < 24) ap = FW + ((size_t)t*B_ + b)*KTOT + (kc - 16)*32 + quad*8;      // x
    else              ap = BW + ((size_t)t*B_ + b)*KTOT + IN_ + (kc - 24)*32 + quad*8;// c_right
    const bf16x8 af = *(const bf16x8*)ap;
    #pragma unroll
    for (int nt = 0; nt < 32; ++nt) {
      bf16x8 bfv = *(const bf16x8*)(&bsm[(nt*64 + lane)*8]);
      acc[nt] = __builtin_amdgcn_mfma_f32_16x16x32_bf16(af, bfv, acc[nt], 0, 0, 0);
    }
  }
  // max over this wave's 16 t-rows, per column
  #pragma unroll
  for (int nt = 0; nt < 32; ++nt) {
    float m = fmaxf(fmaxf(acc[nt][0], acc[nt][1]), fmaxf(acc[nt][2], acc[nt][3]));
    m = fmaxf(m, __shfl_xor(m, 16, 64));
    m = fmaxf(m, __shfl_xor(m, 32, 64));
    if (quad == 0) red[wave*512 + nt*16 + l16] = m;
  }
  __syncthreads();
  {
    float m = red[tid];
    #pragma unroll
    for (int w = 1; w < 8; ++w) m = fmaxf(m, red[w*512 + tid]);
    m = fmaxf(m + fcb[tid], 0.f);   // bias then relu (pool init 0 keeps relu floor)
    atomicMax((int*)&pool[(size_t)b*HID_ + tid], __float_as_int(m));
  }
}

// --------------------------------------------------------------- mlp ----
__global__ void mlp_kernel(const float* __restrict__ pool, const float* __restrict__ w,
                           const float* __restrict__ bias, float* __restrict__ out)
{
  __shared__ float p[HID_];
  const int b = blockIdx.x, tid = threadIdx.x;  // 256 threads
  p[tid]       = pool[(size_t)b*HID_ + tid];
  p[tid + 256] = pool[(size_t)b*HID_ + 256 + tid];
  __syncthreads();
  float acc = bias[tid];
  for (int k = 0; k < HID_; ++k) acc += p[k] * w[(size_t)k*OUT_ + tid];
  out[(size_t)b*OUT_ + tid] = acc;
}

// ------------------------------------------------------------ launch ----
extern "C" void kernel_launch(void* const* d_in, const int* in_sizes, int n_in,
                              void* d_out, int out_size, void* d_ws, size_t ws_size,
                              hipStream_t stream)
{
  const float* x    = (const float*)d_in[0];
  const float* fwWg = (const float*)d_in[1];
  const float* fwbg = (const float*)d_in[2];
  const float* fwWc = (const float*)d_in[3];
  const float* fwbc = (const float*)d_in[4];
  const float* bwWg = (const float*)d_in[5];
  const float* bwbg = (const float*)d_in[6];
  const float* bwWc = (const float*)d_in[7];
  const float* bwbc = (const float*)d_in[8];
  const float* fcw  = (const float*)d_in[9];
  const float* fcb  = (const float*)d_in[10];
  const float* mlpw = (const float*)d_in[11];
  const float* mlpb = (const float*)d_in[12];
  float* out = (float*)d_out;

  char* p = (char*)d_ws;
  auto take = [&](size_t bytes) { char* r = p; p += (bytes + 255) & ~size_t(255); return r; };
  unsigned short* FW   = (unsigned short*)take((size_t)S_*B_*KTOT*2);   // 25.2MB
  unsigned short* BW   = (unsigned short*)take((size_t)S_*B_*KTOT*2);   // 25.2MB
  unsigned short* rh   = (unsigned short*)take((size_t)2*B_*HID_*2);
  unsigned short* fcwf = (unsigned short*)take((size_t)40*32*64*8*2);   // 1.25MB
  float*          pool = (float*)take((size_t)B_*HID_*4);
  unsigned*       bars = (unsigned*)take(256);

  prep_kernel<<<2048, 256, 0, stream>>>(x, fcw, FW, BW, pool, bars, fcwf);
  gru_kernel<<<32, 512, 0, stream>>>(fwWg, fwbg, fwWc, fwbc,
                                     bwWg, bwbg, bwWc, bwbc,
                                     FW, BW, rh, bars);
  fc_kernel<<<128, 512, 0, stream>>>(FW, BW, fcwf, fcb, pool);
  mlp_kernel<<<32, 256, 0, stream>>>(pool, mlpw, mlpb, out);
}